// Round 2
// baseline (582.179 us; speedup 1.0000x reference)
//
#include <hip/hip_runtime.h>
#include <hip/hip_bf16.h>

#define NN     8192
#define INF_   256
#define OF     128
#define EMBD   16
#define QB     32
#define JB     128
#define NST    (NN / JB)      // 64 j-tiles total
#define JSPLIT 4
#define NSTP   (NST / JSPLIT) // 16 tiles per partial block

typedef __attribute__((ext_vector_type(4))) float f32x4;
typedef __attribute__((ext_vector_type(8))) short s16x8;

__device__ __forceinline__ unsigned short f2bf(float x) {
  unsigned u = __builtin_bit_cast(unsigned, x);
  return (unsigned short)((u + 0x7FFFu + ((u >> 16) & 1u)) >> 16);
}

__device__ __forceinline__ float fexp2(float x) {
#if __has_builtin(__builtin_amdgcn_exp2f)
  return __builtin_amdgcn_exp2f(x);
#else
  return exp2f(x);
#endif
}

// ---- K1: hh = eps + h @ W_fc  (f32, register 2x4-tile, f32x4 loads) ----
__global__ __launch_bounds__(256) void k_hh(const float* __restrict__ h,
                                            const float* __restrict__ eps,
                                            const float* __restrict__ Wfc,
                                            float* __restrict__ hh) {
  const int tx = threadIdx.x & 31;       // col quad: cols tx*4..+3
  const int ty = threadIdx.x >> 5;       // 0..7
  const int i0 = blockIdx.x * 16 + ty * 2;
  const int c  = tx * 4;
  f32x4 a0 = *(const f32x4*)&eps[(size_t)i0 * OF + c];
  f32x4 a1 = *(const f32x4*)&eps[(size_t)(i0 + 1) * OF + c];
  const float* h0 = h + (size_t)i0 * INF_;
  const float* h1 = h0 + INF_;
#pragma unroll 2
  for (int kk = 0; kk < INF_; kk += 4) {
    const f32x4 ha = *(const f32x4*)&h0[kk];
    const f32x4 hb = *(const f32x4*)&h1[kk];
#pragma unroll
    for (int u = 0; u < 4; ++u) {
      const f32x4 wv = *(const f32x4*)&Wfc[(size_t)(kk + u) * OF + c];
      a0 += ha[u] * wv;
      a1 += hb[u] * wv;
    }
  }
  *(f32x4*)&hh[(size_t)i0 * OF + c]       = a0;
  *(f32x4*)&hh[(size_t)(i0 + 1) * OF + c] = a1;
}

// ---- K2: k' = (hh @ W_k) * log2(e), q = hh @ W_q  (4 outputs/thread) ----
__global__ __launch_bounds__(256) void k_kq(const float* __restrict__ hh,
                                            const float* __restrict__ Wk,
                                            const float* __restrict__ Wq,
                                            float* __restrict__ kp,
                                            float* __restrict__ qp) {
  const int t   = blockIdx.x * 256 + threadIdx.x;   // 8192*8 threads
  const int i   = t >> 3;
  const int sub = t & 7;
  const float* W = (sub < 4) ? Wk : Wq;
  const int e    = (sub & 3) * 4;
  const float* hr = hh + (size_t)i * OF;
  f32x4 acc = {0.f, 0.f, 0.f, 0.f};
#pragma unroll 4
  for (int o = 0; o < OF; o += 4) {
    const f32x4 hv = *(const f32x4*)&hr[o];
#pragma unroll
    for (int u = 0; u < 4; ++u) {
      const f32x4 wv = *(const f32x4*)&W[(size_t)(o + u) * EMBD + e];
      acc += hv[u] * wv;
    }
  }
  if (sub < 4) {
    acc *= 1.4426950408889634f;
    *(f32x4*)&kp[(size_t)i * EMBD + e] = acc;
  } else {
    *(f32x4*)&qp[(size_t)i * EMBD + e] = acc;
  }
}

// ---- K3: hhT (bf16) [OF][NN] = transpose(hh) ----
__global__ __launch_bounds__(256) void k_tr(const float* __restrict__ hh,
                                            short* __restrict__ hhT) {
  __shared__ float tile[64][65];
  const int i0 = blockIdx.x * 64;
  const int o0 = blockIdx.y * 64;
  const int c = threadIdx.x & 63;
  const int r = threadIdx.x >> 6;
#pragma unroll
  for (int rr = 0; rr < 16; ++rr) {
    const int ii = rr * 4 + r;
    tile[ii][c] = hh[(size_t)(i0 + ii) * OF + o0 + c];
  }
  __syncthreads();
#pragma unroll
  for (int rr = 0; rr < 16; ++rr) {
    const int oo = rr * 4 + r;
    hhT[(size_t)(o0 + oo) * NN + i0 + c] = (short)f2bf(tile[c][oo]);
  }
}

// ---- K4: fused masked-attention partial pass (j-split) ----
// block (bx, p): rows rb..rb+31, j in [p*2048, (p+1)*2048)
// stores unnormalized acc (f32) + (m, d) per row to workspace
__global__ __launch_bounds__(512, 4) void k_attn(const float* __restrict__ Astr,
                                                 const float* __restrict__ kp,
                                                 const float* __restrict__ qp,
                                                 const short* __restrict__ hhT,
                                                 float* __restrict__ accP,
                                                 float* __restrict__ mdP) {
  __shared__ __align__(16) float qbuf[2][JB * EMBD];  // XOR-granule swizzled
  __shared__ __align__(16) short wbuf[2][QB * JB];    // bf16 weights, swizzled
  __shared__ float fscale[2][QB];

  const int tid = threadIdx.x;
  const int l   = tid & 63;
  const int w   = tid >> 6;
  const int row = tid >> 4;   // s-role: 0..31
  const int g   = tid & 15;   // s-role: j-octet
  const int rt  = w >> 2;     // mfma-role: row-tile 0..1
  const int ctp = w & 3;      // mfma-role: 32-col group
  const int h4  = l >> 4;
  const int ln  = l & 15;
  const int rb  = blockIdx.x * QB;
  const int p   = blockIdx.y;
  const int t0  = p * NSTP;
  const int jr  = tid >> 2;   // q-stage role: 0..127
  const int e4  = tid & 3;

  float kreg[16];
  {
    const f32x4* kv = (const f32x4*)(kp + (size_t)(rb + row) * EMBD);
#pragma unroll
    for (int i = 0; i < 4; ++i) {
      f32x4 v = kv[i];
      kreg[i * 4 + 0] = v.x; kreg[i * 4 + 1] = v.y;
      kreg[i * 4 + 2] = v.z; kreg[i * 4 + 3] = v.w;
    }
  }
  f32x4 acc0 = {0.f, 0.f, 0.f, 0.f};
  f32x4 acc1 = {0.f, 0.f, 0.f, 0.f};
  float mrun = -1e30f;
  float dpart = 0.f;

  const size_t arow = (size_t)(rb + row) * NN;
  const int swzw = row & 7;   // wbuf octet swizzle for this row
  const int ra   = rt * 16 + ln;
  const int qsw  = g & 7;     // qbuf granule swizzle for score reads

  // prologue: stage q tile t0, prefetch a_str tile t0
  {
    f32x4 v = *(const f32x4*)(qp + (size_t)(t0 * JB + jr) * EMBD + e4 * 4);
    const int gi = (jr * 4 + e4) ^ ((jr >> 3) & 7);
    *(f32x4*)&qbuf[0][gi * 4] = v;
  }
  f32x4 aA[2], aB[2];
  aA[0] = *(const f32x4*)(Astr + arow + t0 * JB + g * 8);
  aA[1] = *(const f32x4*)(Astr + arow + t0 * JB + g * 8 + 4);
  __syncthreads();

  auto STEP = [&](int t, f32x4 (&acur)[2], f32x4 (&anxt)[2], int par) {
    const int jb = t * JB;
    const int tn = (t + 1 < t0 + NSTP) ? (t + 1) : t0;
    const int jn = tn * JB;
    // phase 1a: next q tile -> regs
    f32x4 qv = *(const f32x4*)(qp + (size_t)(jn + jr) * EMBD + e4 * 4);
    // phase 1b: B-fragments for current tile (L2-resident hhT)
    s16x8 bfr[2][4];
#pragma unroll
    for (int cc = 0; cc < 2; ++cc) {
      const size_t bbase = (size_t)(ctp * 32 + cc * 16 + ln) * NN + jb + h4 * 8;
#pragma unroll
      for (int kt = 0; kt < 4; ++kt)
        bfr[cc][kt] = *(const s16x8*)(hhT + bbase + kt * 32);
    }
    // phase 1c: a_str prefetch for next tile (HBM stream)
    anxt[0] = *(const f32x4*)(Astr + arow + jn + g * 8);
    anxt[1] = *(const f32x4*)(Astr + arow + jn + g * 8 + 4);
    // phase 2: scores (f32, log2-units; thread's j = g*8 + jj)
    float s[8];
#pragma unroll
    for (int jj = 0; jj < 8; ++jj) {
      const int r4 = (g * 8 + jj) * 4;
      const f32x4 q0 = *(const f32x4*)&qbuf[par][((r4 + 0) ^ qsw) * 4];
      const f32x4 q1 = *(const f32x4*)&qbuf[par][((r4 + 1) ^ qsw) * 4];
      const f32x4 q2 = *(const f32x4*)&qbuf[par][((r4 + 2) ^ qsw) * 4];
      const f32x4 q3 = *(const f32x4*)&qbuf[par][((r4 + 3) ^ qsw) * 4];
      float u0 = kreg[0] * q0.x, u1 = kreg[1] * q0.y;
      u0 = fmaf(kreg[2],  q0.z, u0); u1 = fmaf(kreg[3],  q0.w, u1);
      u0 = fmaf(kreg[4],  q1.x, u0); u1 = fmaf(kreg[5],  q1.y, u1);
      u0 = fmaf(kreg[6],  q1.z, u0); u1 = fmaf(kreg[7],  q1.w, u1);
      u0 = fmaf(kreg[8],  q2.x, u0); u1 = fmaf(kreg[9],  q2.y, u1);
      u0 = fmaf(kreg[10], q2.z, u0); u1 = fmaf(kreg[11], q2.w, u1);
      u0 = fmaf(kreg[12], q3.x, u0); u1 = fmaf(kreg[13], q3.y, u1);
      u0 = fmaf(kreg[14], q3.z, u0); u1 = fmaf(kreg[15], q3.w, u1);
      s[jj] = u0 + u1;
    }
    // phase 3: online max + weights
    float tmax = s[0];
#pragma unroll
    for (int jj = 1; jj < 8; ++jj) tmax = fmaxf(tmax, s[jj]);
    tmax = fmaxf(tmax, __shfl_xor(tmax, 1, 16));
    tmax = fmaxf(tmax, __shfl_xor(tmax, 2, 16));
    tmax = fmaxf(tmax, __shfl_xor(tmax, 4, 16));
    tmax = fmaxf(tmax, __shfl_xor(tmax, 8, 16));
    const float mnew = fmaxf(mrun, tmax);
    const float f = fexp2(mrun - mnew);
    mrun = mnew;
    dpart *= f;
    s16x8 wpack;
    {
      const float* ac = (const float*)&acur[0];
#pragma unroll
      for (int jj = 0; jj < 8; ++jj) {
        const float wv = ac[jj] * fexp2(s[jj] - mnew);
        dpart += wv;
        wpack[jj] = (short)f2bf(wv);
      }
    }
    *(s16x8*)&wbuf[par][row * JB + ((g ^ swzw) * 8)] = wpack;
    if (g == 0) fscale[par][row] = f;
    // phase 3.5: complete q stage into other buffer
    {
      const int gi = (jr * 4 + e4) ^ ((jr >> 3) & 7);
      *(f32x4*)&qbuf[par ^ 1][gi * 4] = qv;
    }
    __syncthreads();
    // phase 5: rescale accumulators, then PV MFMA
#pragma unroll
    for (int r = 0; r < 4; ++r) {
      const float fr = fscale[par][rt * 16 + 4 * h4 + r];
      acc0[r] *= fr;
      acc1[r] *= fr;
    }
    s16x8 afr[4];
#pragma unroll
    for (int kt = 0; kt < 4; ++kt)
      afr[kt] = *(const s16x8*)&wbuf[par][ra * JB + (((kt * 4 + h4) ^ (ra & 7)) * 8)];
#pragma unroll
    for (int kt = 0; kt < 4; ++kt) {
      acc0 = __builtin_amdgcn_mfma_f32_16x16x32_bf16(afr[kt], bfr[0][kt], acc0, 0, 0, 0);
      acc1 = __builtin_amdgcn_mfma_f32_16x16x32_bf16(afr[kt], bfr[1][kt], acc1, 0, 0, 0);
    }
  };

  for (int t = t0; t < t0 + NSTP; t += 2) {
    STEP(t,     aA, aB, 0);
    STEP(t + 1, aB, aA, 1);
  }

  // epilogue: reduce denominator, store partials (no normalization here)
  float d = dpart;
  d += __shfl_xor(d, 1, 16);
  d += __shfl_xor(d, 2, 16);
  d += __shfl_xor(d, 4, 16);
  d += __shfl_xor(d, 8, 16);
  if (g == 0) {
    mdP[((size_t)p * NN + rb + row) * 2 + 0] = mrun;
    mdP[((size_t)p * NN + rb + row) * 2 + 1] = d;
  }
#pragma unroll
  for (int r = 0; r < 4; ++r) {
    const int lrow = rt * 16 + 4 * h4 + r;
    float* orow = accP + ((size_t)p * NN + rb + lrow) * OF + ctp * 32 + ln;
    orow[0]  = acc0[r];
    orow[16] = acc1[r];
  }
}

// ---- K5: combine j-split partials ----
__global__ __launch_bounds__(256) void k_comb(const float* __restrict__ accP,
                                              const float* __restrict__ mdP,
                                              float* __restrict__ out) {
  const int idx = blockIdx.x * 256 + threadIdx.x;  // over NN*OF
  const int row = idx >> 7;
  const int c   = idx & 127;
  float m[JSPLIT], dd[JSPLIT];
#pragma unroll
  for (int pp = 0; pp < JSPLIT; ++pp) {
    m[pp]  = mdP[((size_t)pp * NN + row) * 2 + 0];
    dd[pp] = mdP[((size_t)pp * NN + row) * 2 + 1];
  }
  float M = m[0];
#pragma unroll
  for (int pp = 1; pp < JSPLIT; ++pp) M = fmaxf(M, m[pp]);
  float D = 0.f, s = 0.f;
#pragma unroll
  for (int pp = 0; pp < JSPLIT; ++pp) {
    const float f = fexp2(m[pp] - M);
    D = fmaf(dd[pp], f, D);
    s = fmaf(accP[((size_t)pp * NN + row) * OF + c], f, s);
  }
  out[(size_t)row * OF + c] = s / D;
}

extern "C" void kernel_launch(void* const* d_in, const int* in_sizes, int n_in,
                              void* d_out, int out_size, void* d_ws, size_t ws_size,
                              hipStream_t stream) {
  const float* h   = (const float*)d_in[0];
  const float* eps = (const float*)d_in[1];
  const float* As  = (const float*)d_in[2];
  const float* Wfc = (const float*)d_in[3];
  const float* Wk  = (const float*)d_in[4];
  const float* Wq  = (const float*)d_in[5];
  float* out = (float*)d_out;

  char* ws = (char*)d_ws;
  float* hh   = (float*)(ws);                              // 4 MB
  short* hhT  = (short*)(ws + (4u << 20));                 // 2 MB
  float* kp   = (float*)(ws + (6u << 20));                 // 512 KB
  float* qp   = (float*)(ws + (6u << 20) + (512u << 10));  // 512 KB
  float* accP = (float*)(ws + (7u << 20));                 // 16 MB
  float* mdP  = (float*)(ws + (23u << 20));                // 256 KB

  k_hh<<<NN / 16, 256, 0, stream>>>(h, eps, Wfc, hh);
  k_kq<<<(NN * 8) / 256, 256, 0, stream>>>(hh, Wk, Wq, kp, qp);
  k_tr<<<dim3(NN / 64, OF / 64), 256, 0, stream>>>(hh, hhT);
  k_attn<<<dim3(NN / QB, JSPLIT), 512, 0, stream>>>(As, kp, qp, hhT, accP, mdP);
  k_comb<<<(NN * OF) / 256, 256, 0, stream>>>(accP, mdP, out);
}

// Round 4
// 513.246 us; speedup vs baseline: 1.1343x; 1.1343x over previous
//
#include <hip/hip_runtime.h>
#include <hip/hip_bf16.h>

#define NN     8192
#define INF_   256
#define OF     128
#define EMBD   16
#define QB     32
#define JB     128
#define NST    (NN / JB)      // 64 j-tiles total
#define JSPLIT 4
#define NSTP   (NST / JSPLIT) // 16 tiles per partial block

typedef __attribute__((ext_vector_type(4))) float f32x4;
typedef __attribute__((ext_vector_type(8))) short s16x8;

__device__ __forceinline__ unsigned short f2bf(float x) {
  unsigned u = __builtin_bit_cast(unsigned, x);
  return (unsigned short)((u + 0x7FFFu + ((u >> 16) & 1u)) >> 16);
}

__device__ __forceinline__ float fexp2(float x) {
#if __has_builtin(__builtin_amdgcn_exp2f)
  return __builtin_amdgcn_exp2f(x);
#else
  return exp2f(x);
#endif
}

// ---- K1: hh = eps + h @ W_fc  (f32, register 2x4-tile, f32x4 loads) ----
__global__ __launch_bounds__(256) void k_hh(const float* __restrict__ h,
                                            const float* __restrict__ eps,
                                            const float* __restrict__ Wfc,
                                            float* __restrict__ hh) {
  const int tx = threadIdx.x & 31;       // col quad: cols tx*4..+3
  const int ty = threadIdx.x >> 5;       // 0..7
  const int i0 = blockIdx.x * 16 + ty * 2;
  const int c  = tx * 4;
  f32x4 a0 = *(const f32x4*)&eps[(size_t)i0 * OF + c];
  f32x4 a1 = *(const f32x4*)&eps[(size_t)(i0 + 1) * OF + c];
  const float* h0 = h + (size_t)i0 * INF_;
  const float* h1 = h0 + INF_;
#pragma unroll 2
  for (int kk = 0; kk < INF_; kk += 4) {
    const f32x4 ha = *(const f32x4*)&h0[kk];
    const f32x4 hb = *(const f32x4*)&h1[kk];
#pragma unroll
    for (int u = 0; u < 4; ++u) {
      const f32x4 wv = *(const f32x4*)&Wfc[(size_t)(kk + u) * OF + c];
      a0 += ha[u] * wv;
      a1 += hb[u] * wv;
    }
  }
  *(f32x4*)&hh[(size_t)i0 * OF + c]       = a0;
  *(f32x4*)&hh[(size_t)(i0 + 1) * OF + c] = a1;
}

// ---- K2: k' = (hh @ W_k) * log2(e), q = hh @ W_q  (4 outputs/thread) ----
__global__ __launch_bounds__(256) void k_kq(const float* __restrict__ hh,
                                            const float* __restrict__ Wk,
                                            const float* __restrict__ Wq,
                                            float* __restrict__ kp,
                                            float* __restrict__ qp) {
  const int t   = blockIdx.x * 256 + threadIdx.x;   // 8192*8 threads
  const int i   = t >> 3;
  const int sub = t & 7;
  const float* W = (sub < 4) ? Wk : Wq;
  const int e    = (sub & 3) * 4;
  const float* hr = hh + (size_t)i * OF;
  f32x4 acc = {0.f, 0.f, 0.f, 0.f};
#pragma unroll 4
  for (int o = 0; o < OF; o += 4) {
    const f32x4 hv = *(const f32x4*)&hr[o];
#pragma unroll
    for (int u = 0; u < 4; ++u) {
      const f32x4 wv = *(const f32x4*)&W[(size_t)(o + u) * EMBD + e];
      acc += hv[u] * wv;
    }
  }
  if (sub < 4) {
    acc *= 1.4426950408889634f;
    *(f32x4*)&kp[(size_t)i * EMBD + e] = acc;
  } else {
    *(f32x4*)&qp[(size_t)i * EMBD + e] = acc;
  }
}

// ---- K3: hhT (bf16) [OF][NN] = transpose(hh) ----
__global__ __launch_bounds__(256) void k_tr(const float* __restrict__ hh,
                                            short* __restrict__ hhT) {
  __shared__ float tile[64][65];
  const int i0 = blockIdx.x * 64;
  const int o0 = blockIdx.y * 64;
  const int c = threadIdx.x & 63;
  const int r = threadIdx.x >> 6;
#pragma unroll
  for (int rr = 0; rr < 16; ++rr) {
    const int ii = rr * 4 + r;
    tile[ii][c] = hh[(size_t)(i0 + ii) * OF + o0 + c];
  }
  __syncthreads();
#pragma unroll
  for (int rr = 0; rr < 16; ++rr) {
    const int oo = rr * 4 + r;
    hhT[(size_t)(o0 + oo) * NN + i0 + c] = (short)f2bf(tile[c][oo]);
  }
}

// ---- K4: fused masked-attention partial pass (j-split) ----
// block (bx, p): rows rb..rb+31, j in [p*2048, (p+1)*2048)
// stores unnormalized acc (f32) + (m, d) per row to workspace
__global__ __launch_bounds__(512, 2) void k_attn(const float* __restrict__ Astr,
                                                 const float* __restrict__ kp,
                                                 const float* __restrict__ qp,
                                                 const short* __restrict__ hhT,
                                                 float* __restrict__ accP,
                                                 float* __restrict__ mdP) {
  __shared__ __align__(16) float qbuf[2][JB * EMBD];  // XOR-granule swizzled
  __shared__ __align__(16) short wbuf[2][QB * JB];    // bf16 weights, swizzled
  __shared__ float fscale[2][QB];

  const int tid = threadIdx.x;
  const int l   = tid & 63;
  const int w   = tid >> 6;
  const int row = tid >> 4;   // s-role: 0..31
  const int g   = tid & 15;   // s-role: j-octet
  const int rt  = w >> 2;     // mfma-role: row-tile 0..1
  const int ctp = w & 3;      // mfma-role: 32-col group
  const int h4  = l >> 4;
  const int ln  = l & 15;
  const int rb  = blockIdx.x * QB;
  const int p   = blockIdx.y;
  const int t0  = p * NSTP;
  const int jr  = tid >> 2;   // q-stage role: 0..127
  const int e4  = tid & 3;

  float kreg[16];
  {
    const f32x4* kv = (const f32x4*)(kp + (size_t)(rb + row) * EMBD);
#pragma unroll
    for (int i = 0; i < 4; ++i) {
      f32x4 v = kv[i];
      kreg[i * 4 + 0] = v.x; kreg[i * 4 + 1] = v.y;
      kreg[i * 4 + 2] = v.z; kreg[i * 4 + 3] = v.w;
    }
  }
  f32x4 acc0 = {0.f, 0.f, 0.f, 0.f};
  f32x4 acc1 = {0.f, 0.f, 0.f, 0.f};
  float mrun = -1e30f;
  float dpart = 0.f;

  const size_t arow = (size_t)(rb + row) * NN;
  const int swzw = row & 7;   // wbuf octet swizzle for this row
  const int ra   = rt * 16 + ln;
  const int qsw  = g & 7;     // qbuf granule swizzle for score reads

  // prologue: stage q tile t0, prefetch a_str tile t0
  {
    f32x4 v = *(const f32x4*)(qp + (size_t)(t0 * JB + jr) * EMBD + e4 * 4);
    const int gi = (jr * 4 + e4) ^ ((jr >> 3) & 7);
    *(f32x4*)&qbuf[0][gi * 4] = v;
  }
  f32x4 aA[2], aB[2];
  aA[0] = *(const f32x4*)(Astr + arow + t0 * JB + g * 8);
  aA[1] = *(const f32x4*)(Astr + arow + t0 * JB + g * 8 + 4);
  __syncthreads();

  auto STEP = [&](int t, f32x4 (&acur)[2], f32x4 (&anxt)[2], int par) {
    const int jb = t * JB;
    const int tn = (t + 1 < t0 + NSTP) ? (t + 1) : t0;
    const int jn = tn * JB;
    // phase 1a: next q tile -> regs
    f32x4 qv = *(const f32x4*)(qp + (size_t)(jn + jr) * EMBD + e4 * 4);
    // phase 1b: B-fragments for current tile (L2-resident hhT)
    s16x8 bfr[2][4];
#pragma unroll
    for (int cc = 0; cc < 2; ++cc) {
      const size_t bbase = (size_t)(ctp * 32 + cc * 16 + ln) * NN + jb + h4 * 8;
#pragma unroll
      for (int kt = 0; kt < 4; ++kt)
        bfr[cc][kt] = *(const s16x8*)(hhT + bbase + kt * 32);
    }
    // phase 1c: a_str prefetch for next tile (HBM stream)
    anxt[0] = *(const f32x4*)(Astr + arow + jn + g * 8);
    anxt[1] = *(const f32x4*)(Astr + arow + jn + g * 8 + 4);
    // phase 2: scores (f32, log2-units; thread's j = g*8 + jj)
    float s[8];
#pragma unroll
    for (int jj = 0; jj < 8; ++jj) {
      const int r4 = (g * 8 + jj) * 4;
      const f32x4 q0 = *(const f32x4*)&qbuf[par][((r4 + 0) ^ qsw) * 4];
      const f32x4 q1 = *(const f32x4*)&qbuf[par][((r4 + 1) ^ qsw) * 4];
      const f32x4 q2 = *(const f32x4*)&qbuf[par][((r4 + 2) ^ qsw) * 4];
      const f32x4 q3 = *(const f32x4*)&qbuf[par][((r4 + 3) ^ qsw) * 4];
      float u0 = kreg[0] * q0.x, u1 = kreg[1] * q0.y;
      u0 = fmaf(kreg[2],  q0.z, u0); u1 = fmaf(kreg[3],  q0.w, u1);
      u0 = fmaf(kreg[4],  q1.x, u0); u1 = fmaf(kreg[5],  q1.y, u1);
      u0 = fmaf(kreg[6],  q1.z, u0); u1 = fmaf(kreg[7],  q1.w, u1);
      u0 = fmaf(kreg[8],  q2.x, u0); u1 = fmaf(kreg[9],  q2.y, u1);
      u0 = fmaf(kreg[10], q2.z, u0); u1 = fmaf(kreg[11], q2.w, u1);
      u0 = fmaf(kreg[12], q3.x, u0); u1 = fmaf(kreg[13], q3.y, u1);
      u0 = fmaf(kreg[14], q3.z, u0); u1 = fmaf(kreg[15], q3.w, u1);
      s[jj] = u0 + u1;
    }
    // phase 3: online max + weights
    float tmax = s[0];
#pragma unroll
    for (int jj = 1; jj < 8; ++jj) tmax = fmaxf(tmax, s[jj]);
    tmax = fmaxf(tmax, __shfl_xor(tmax, 1, 16));
    tmax = fmaxf(tmax, __shfl_xor(tmax, 2, 16));
    tmax = fmaxf(tmax, __shfl_xor(tmax, 4, 16));
    tmax = fmaxf(tmax, __shfl_xor(tmax, 8, 16));
    const float mnew = fmaxf(mrun, tmax);
    const float f = fexp2(mrun - mnew);
    mrun = mnew;
    dpart *= f;
    s16x8 wpack;
    {
      const float* ac = (const float*)&acur[0];
#pragma unroll
      for (int jj = 0; jj < 8; ++jj) {
        const float wv = ac[jj] * fexp2(s[jj] - mnew);
        dpart += wv;
        wpack[jj] = (short)f2bf(wv);
      }
    }
    *(s16x8*)&wbuf[par][row * JB + ((g ^ swzw) * 8)] = wpack;
    if (g == 0) fscale[par][row] = f;
    // phase 3.5: complete q stage into other buffer
    {
      const int gi = (jr * 4 + e4) ^ ((jr >> 3) & 7);
      *(f32x4*)&qbuf[par ^ 1][gi * 4] = qv;
    }
    __syncthreads();
    // phase 5: rescale accumulators, then PV MFMA
#pragma unroll
    for (int r = 0; r < 4; ++r) {
      const float fr = fscale[par][rt * 16 + 4 * h4 + r];
      acc0[r] *= fr;
      acc1[r] *= fr;
    }
    s16x8 afr[4];
#pragma unroll
    for (int kt = 0; kt < 4; ++kt)
      afr[kt] = *(const s16x8*)&wbuf[par][ra * JB + (((kt * 4 + h4) ^ (ra & 7)) * 8)];
#pragma unroll
    for (int kt = 0; kt < 4; ++kt) {
      acc0 = __builtin_amdgcn_mfma_f32_16x16x32_bf16(afr[kt], bfr[0][kt], acc0, 0, 0, 0);
      acc1 = __builtin_amdgcn_mfma_f32_16x16x32_bf16(afr[kt], bfr[1][kt], acc1, 0, 0, 0);
    }
  };

  for (int t = t0; t < t0 + NSTP; t += 2) {
    STEP(t,     aA, aB, 0);
    STEP(t + 1, aB, aA, 1);
  }

  // epilogue: reduce denominator, store partials (no normalization here)
  float d = dpart;
  d += __shfl_xor(d, 1, 16);
  d += __shfl_xor(d, 2, 16);
  d += __shfl_xor(d, 4, 16);
  d += __shfl_xor(d, 8, 16);
  if (g == 0) {
    mdP[((size_t)p * NN + rb + row) * 2 + 0] = mrun;
    mdP[((size_t)p * NN + rb + row) * 2 + 1] = d;
  }
#pragma unroll
  for (int r = 0; r < 4; ++r) {
    const int lrow = rt * 16 + 4 * h4 + r;
    float* orow = accP + ((size_t)p * NN + rb + lrow) * OF + ctp * 32 + ln;
    orow[0]  = acc0[r];
    orow[16] = acc1[r];
  }
}

// ---- K5: combine j-split partials ----
__global__ __launch_bounds__(256) void k_comb(const float* __restrict__ accP,
                                              const float* __restrict__ mdP,
                                              float* __restrict__ out) {
  const int idx = blockIdx.x * 256 + threadIdx.x;  // over NN*OF
  const int row = idx >> 7;
  const int c   = idx & 127;
  float m[JSPLIT], dd[JSPLIT];
#pragma unroll
  for (int pp = 0; pp < JSPLIT; ++pp) {
    m[pp]  = mdP[((size_t)pp * NN + row) * 2 + 0];
    dd[pp] = mdP[((size_t)pp * NN + row) * 2 + 1];
  }
  float M = m[0];
#pragma unroll
  for (int pp = 1; pp < JSPLIT; ++pp) M = fmaxf(M, m[pp]);
  float D = 0.f, s = 0.f;
#pragma unroll
  for (int pp = 0; pp < JSPLIT; ++pp) {
    const float f = fexp2(m[pp] - M);
    D = fmaf(dd[pp], f, D);
    s = fmaf(accP[((size_t)pp * NN + row) * OF + c], f, s);
  }
  out[(size_t)row * OF + c] = s / D;
}

extern "C" void kernel_launch(void* const* d_in, const int* in_sizes, int n_in,
                              void* d_out, int out_size, void* d_ws, size_t ws_size,
                              hipStream_t stream) {
  const float* h   = (const float*)d_in[0];
  const float* eps = (const float*)d_in[1];
  const float* As  = (const float*)d_in[2];
  const float* Wfc = (const float*)d_in[3];
  const float* Wk  = (const float*)d_in[4];
  const float* Wq  = (const float*)d_in[5];
  float* out = (float*)d_out;

  char* ws = (char*)d_ws;
  float* hh   = (float*)(ws);                              // 4 MB
  short* hhT  = (short*)(ws + (4u << 20));                 // 2 MB
  float* kp   = (float*)(ws + (6u << 20));                 // 512 KB
  float* qp   = (float*)(ws + (6u << 20) + (512u << 10));  // 512 KB
  float* accP = (float*)(ws + (7u << 20));                 // 16 MB
  float* mdP  = (float*)(ws + (23u << 20));                // 256 KB

  k_hh<<<NN / 16, 256, 0, stream>>>(h, eps, Wfc, hh);
  k_kq<<<(NN * 8) / 256, 256, 0, stream>>>(hh, Wk, Wq, kp, qp);
  k_tr<<<dim3(NN / 64, OF / 64), 256, 0, stream>>>(hh, hhT);
  k_attn<<<dim3(NN / QB, JSPLIT), 512, 0, stream>>>(As, kp, qp, hhT, accP, mdP);
  k_comb<<<(NN * OF) / 256, 256, 0, stream>>>(accP, mdP, out);
}

// Round 5
// 500.316 us; speedup vs baseline: 1.1636x; 1.0258x over previous
//
#include <hip/hip_runtime.h>
#include <hip/hip_bf16.h>

#define NN     8192
#define INF_   256
#define OF     128
#define EMBD   16
#define QB     16
#define JB     128
#define NST    (NN / JB)      // 64 j-tiles total
#define JSPLIT 4
#define NSTP   (NST / JSPLIT) // 16 tiles per partial block

typedef __attribute__((ext_vector_type(4))) float f32x4;
typedef __attribute__((ext_vector_type(8))) short s16x8;

__device__ __forceinline__ unsigned short f2bf(float x) {
  unsigned u = __builtin_bit_cast(unsigned, x);
  return (unsigned short)((u + 0x7FFFu + ((u >> 16) & 1u)) >> 16);
}

__device__ __forceinline__ float fexp2(float x) {
#if __has_builtin(__builtin_amdgcn_exp2f)
  return __builtin_amdgcn_exp2f(x);
#else
  return exp2f(x);
#endif
}

// ---- K1: hh = eps + h @ W_fc  (f32, register 2x4-tile, f32x4 loads) ----
__global__ __launch_bounds__(256) void k_hh(const float* __restrict__ h,
                                            const float* __restrict__ eps,
                                            const float* __restrict__ Wfc,
                                            float* __restrict__ hh) {
  const int tx = threadIdx.x & 31;       // col quad: cols tx*4..+3
  const int ty = threadIdx.x >> 5;       // 0..7
  const int i0 = blockIdx.x * 16 + ty * 2;
  const int c  = tx * 4;
  f32x4 a0 = *(const f32x4*)&eps[(size_t)i0 * OF + c];
  f32x4 a1 = *(const f32x4*)&eps[(size_t)(i0 + 1) * OF + c];
  const float* h0 = h + (size_t)i0 * INF_;
  const float* h1 = h0 + INF_;
#pragma unroll 2
  for (int kk = 0; kk < INF_; kk += 4) {
    const f32x4 ha = *(const f32x4*)&h0[kk];
    const f32x4 hb = *(const f32x4*)&h1[kk];
#pragma unroll
    for (int u = 0; u < 4; ++u) {
      const f32x4 wv = *(const f32x4*)&Wfc[(size_t)(kk + u) * OF + c];
      a0 += ha[u] * wv;
      a1 += hb[u] * wv;
    }
  }
  *(f32x4*)&hh[(size_t)i0 * OF + c]       = a0;
  *(f32x4*)&hh[(size_t)(i0 + 1) * OF + c] = a1;
}

// ---- K2: k' = (hh @ W_k) * log2(e), q = hh @ W_q  (4 outputs/thread) ----
__global__ __launch_bounds__(256) void k_kq(const float* __restrict__ hh,
                                            const float* __restrict__ Wk,
                                            const float* __restrict__ Wq,
                                            float* __restrict__ kp,
                                            float* __restrict__ qp) {
  const int t   = blockIdx.x * 256 + threadIdx.x;   // 8192*8 threads
  const int i   = t >> 3;
  const int sub = t & 7;
  const float* W = (sub < 4) ? Wk : Wq;
  const int e    = (sub & 3) * 4;
  const float* hr = hh + (size_t)i * OF;
  f32x4 acc = {0.f, 0.f, 0.f, 0.f};
#pragma unroll 4
  for (int o = 0; o < OF; o += 4) {
    const f32x4 hv = *(const f32x4*)&hr[o];
#pragma unroll
    for (int u = 0; u < 4; ++u) {
      const f32x4 wv = *(const f32x4*)&W[(size_t)(o + u) * EMBD + e];
      acc += hv[u] * wv;
    }
  }
  if (sub < 4) {
    acc *= 1.4426950408889634f;
    *(f32x4*)&kp[(size_t)i * EMBD + e] = acc;
  } else {
    *(f32x4*)&qp[(size_t)i * EMBD + e] = acc;
  }
}

// ---- K3: hhT (bf16) [OF][NN] = transpose(hh) ----
__global__ __launch_bounds__(256) void k_tr(const float* __restrict__ hh,
                                            short* __restrict__ hhT) {
  __shared__ float tile[64][65];
  const int i0 = blockIdx.x * 64;
  const int o0 = blockIdx.y * 64;
  const int c = threadIdx.x & 63;
  const int r = threadIdx.x >> 6;
#pragma unroll
  for (int rr = 0; rr < 16; ++rr) {
    const int ii = rr * 4 + r;
    tile[ii][c] = hh[(size_t)(i0 + ii) * OF + o0 + c];
  }
  __syncthreads();
#pragma unroll
  for (int rr = 0; rr < 16; ++rr) {
    const int oo = rr * 4 + r;
    hhT[(size_t)(o0 + oo) * NN + i0 + c] = (short)f2bf(tile[c][oo]);
  }
}

// ---- K4: fused masked-attention partial pass, no-max variant ----
// weights = a_str * 2^(s - 32)  (s = k'.q in log2 units); partials combine
// exactly in k_comb: out = (sum_p acc_p) / (sum_p d_p).
__global__ __launch_bounds__(256) void k_attn(const float* __restrict__ Astr,
                                              const float* __restrict__ kp,
                                              const float* __restrict__ qp,
                                              const short* __restrict__ hhT,
                                              float* __restrict__ accP,
                                              float* __restrict__ dP) {
  __shared__ __align__(16) float qbuf[2][JB * EMBD];  // 16B-granule swizzled
  __shared__ __align__(16) short wbuf[2][QB * JB];    // bf16 weights, swizzled

  const int tid = threadIdx.x;
  const int l   = tid & 63;
  const int row = tid >> 4;   // s-role: 0..15
  const int g   = tid & 15;   // s-role: j-octet
  const int ctp = tid >> 6;   // mfma-role: 32-col group (0..3)
  const int h4  = l >> 4;
  const int ln  = l & 15;
  const int rb  = blockIdx.x * QB;
  const int p   = blockIdx.y;
  const int t0  = p * NSTP;
  const int jr  = tid >> 1;          // q-stage role: 0..127
  const int eh  = (tid & 1) * 2;     // granule pair base (e4 = eh, eh+1)

  float kreg[16];
  {
    const f32x4* kv = (const f32x4*)(kp + (size_t)(rb + row) * EMBD);
#pragma unroll
    for (int i = 0; i < 4; ++i) {
      f32x4 v = kv[i];
      kreg[i * 4 + 0] = v.x; kreg[i * 4 + 1] = v.y;
      kreg[i * 4 + 2] = v.z; kreg[i * 4 + 3] = v.w;
    }
  }
  f32x4 acc0 = {0.f, 0.f, 0.f, 0.f};
  f32x4 acc1 = {0.f, 0.f, 0.f, 0.f};
  float dpart = 0.f;

  const size_t arow = (size_t)(rb + row) * NN;
  const int swzw = row & 7;   // wbuf octet swizzle for this row
  const int qsw0 = (jr >> 3) & 7;

  // prologue: stage q tile t0, prefetch a_str tile t0
  {
    const float* src = qp + (size_t)(t0 * JB + jr) * EMBD + eh * 4;
    f32x4 v0 = *(const f32x4*)src;
    f32x4 v1 = *(const f32x4*)(src + 4);
    *(f32x4*)&qbuf[0][((jr * 4 + eh)     ^ qsw0) * 4] = v0;
    *(f32x4*)&qbuf[0][((jr * 4 + eh + 1) ^ qsw0) * 4] = v1;
  }
  f32x4 aA[2], aB[2];
  aA[0] = *(const f32x4*)(Astr + arow + t0 * JB + g * 8);
  aA[1] = *(const f32x4*)(Astr + arow + t0 * JB + g * 8 + 4);
  __syncthreads();

  auto STEP = [&](int t, f32x4 (&acur)[2], f32x4 (&anxt)[2], int par) {
    const int jb = t * JB;
    const int tn = (t + 1 < t0 + NSTP) ? (t + 1) : t0;
    const int jn = tn * JB;
    // phase 1a: next q tile -> regs
    const float* qsrc = qp + (size_t)(jn + jr) * EMBD + eh * 4;
    f32x4 qv0 = *(const f32x4*)qsrc;
    f32x4 qv1 = *(const f32x4*)(qsrc + 4);
    // phase 1b: B-fragments for current tile (L2-resident hhT)
    s16x8 bfr[2][4];
#pragma unroll
    for (int cc = 0; cc < 2; ++cc) {
      const size_t bbase = (size_t)(ctp * 32 + cc * 16 + ln) * NN + jb + h4 * 8;
#pragma unroll
      for (int kt = 0; kt < 4; ++kt)
        bfr[cc][kt] = *(const s16x8*)(hhT + bbase + kt * 32);
    }
    // phase 1c: a_str prefetch for next tile (HBM stream)
    anxt[0] = *(const f32x4*)(Astr + arow + jn + g * 8);
    anxt[1] = *(const f32x4*)(Astr + arow + jn + g * 8 + 4);
    // phase 2: scores (f32, log2 units; thread's j = g*8 + jj)
    float s[8];
#pragma unroll
    for (int jj = 0; jj < 8; ++jj) {
      const int j  = g * 8 + jj;
      const int sw = (j >> 3) & 7;   // == g
      const f32x4 q0 = *(const f32x4*)&qbuf[par][((j * 4 + 0) ^ sw) * 4];
      const f32x4 q1 = *(const f32x4*)&qbuf[par][((j * 4 + 1) ^ sw) * 4];
      const f32x4 q2 = *(const f32x4*)&qbuf[par][((j * 4 + 2) ^ sw) * 4];
      const f32x4 q3 = *(const f32x4*)&qbuf[par][((j * 4 + 3) ^ sw) * 4];
      float u0 = kreg[0] * q0.x, u1 = kreg[1] * q0.y;
      u0 = fmaf(kreg[2],  q0.z, u0); u1 = fmaf(kreg[3],  q0.w, u1);
      u0 = fmaf(kreg[4],  q1.x, u0); u1 = fmaf(kreg[5],  q1.y, u1);
      u0 = fmaf(kreg[6],  q1.z, u0); u1 = fmaf(kreg[7],  q1.w, u1);
      u0 = fmaf(kreg[8],  q2.x, u0); u1 = fmaf(kreg[9],  q2.y, u1);
      u0 = fmaf(kreg[10], q2.z, u0); u1 = fmaf(kreg[11], q2.w, u1);
      u0 = fmaf(kreg[12], q3.x, u0); u1 = fmaf(kreg[13], q3.y, u1);
      u0 = fmaf(kreg[14], q3.z, u0); u1 = fmaf(kreg[15], q3.w, u1);
      s[jj] = u0 + u1;
    }
    // phase 3: weights (no max-tracking; fixed 2^-32 shift, +80 clamp)
    s16x8 wpack;
    {
      const float* ac = (const float*)&acur[0];
#pragma unroll
      for (int jj = 0; jj < 8; ++jj) {
        const float wv = ac[jj] * fexp2(fminf(s[jj] - 32.0f, 80.0f));
        dpart += wv;
        wpack[jj] = (short)f2bf(wv);
      }
    }
    *(s16x8*)&wbuf[par][row * JB + ((g ^ swzw) * 8)] = wpack;
    // phase 3.5: complete q stage into other buffer
    *(f32x4*)&qbuf[par ^ 1][((jr * 4 + eh)     ^ qsw0) * 4] = qv0;
    *(f32x4*)&qbuf[par ^ 1][((jr * 4 + eh + 1) ^ qsw0) * 4] = qv1;
    __syncthreads();
    // phase 5: PV MFMA (no rescale needed)
    s16x8 afr[4];
#pragma unroll
    for (int kt = 0; kt < 4; ++kt)
      afr[kt] = *(const s16x8*)&wbuf[par][ln * JB + (((kt * 4 + h4) ^ (ln & 7)) * 8)];
#pragma unroll
    for (int kt = 0; kt < 4; ++kt) {
      acc0 = __builtin_amdgcn_mfma_f32_16x16x32_bf16(afr[kt], bfr[0][kt], acc0, 0, 0, 0);
      acc1 = __builtin_amdgcn_mfma_f32_16x16x32_bf16(afr[kt], bfr[1][kt], acc1, 0, 0, 0);
    }
  };

  for (int t = t0; t < t0 + NSTP; t += 2) {
    STEP(t,     aA, aB, 0);
    STEP(t + 1, aB, aA, 1);
  }

  // epilogue: reduce denominator over the 16 g-lanes, store partials
  float d = dpart;
  d += __shfl_xor(d, 1, 16);
  d += __shfl_xor(d, 2, 16);
  d += __shfl_xor(d, 4, 16);
  d += __shfl_xor(d, 8, 16);
  if (g == 0) dP[(size_t)p * NN + rb + row] = d;
#pragma unroll
  for (int r = 0; r < 4; ++r) {
    const int lrow = h4 * 4 + r;
    float* orow = accP + ((size_t)p * NN + rb + lrow) * OF + ctp * 32 + ln;
    orow[0]  = acc0[r];
    orow[16] = acc1[r];
  }
}

// ---- K5: combine j-split partials (exact: plain sums) ----
__global__ __launch_bounds__(256) void k_comb(const float* __restrict__ accP,
                                              const float* __restrict__ dP,
                                              float* __restrict__ out) {
  const int idx = blockIdx.x * 256 + threadIdx.x;  // over NN*OF/4
  const int row = idx >> 5;
  const int cq  = (idx & 31) * 4;
  float D = 0.f;
  f32x4 s = {0.f, 0.f, 0.f, 0.f};
#pragma unroll
  for (int pp = 0; pp < JSPLIT; ++pp) {
    D += dP[(size_t)pp * NN + row];
    s += *(const f32x4*)&accP[((size_t)pp * NN + row) * OF + cq];
  }
  const float inv = 1.0f / D;
  f32x4 r = s * inv;
  *(f32x4*)&out[(size_t)row * OF + cq] = r;
}

extern "C" void kernel_launch(void* const* d_in, const int* in_sizes, int n_in,
                              void* d_out, int out_size, void* d_ws, size_t ws_size,
                              hipStream_t stream) {
  const float* h   = (const float*)d_in[0];
  const float* eps = (const float*)d_in[1];
  const float* As  = (const float*)d_in[2];
  const float* Wfc = (const float*)d_in[3];
  const float* Wk  = (const float*)d_in[4];
  const float* Wq  = (const float*)d_in[5];
  float* out = (float*)d_out;

  char* ws = (char*)d_ws;
  float* kp   = (float*)(ws);                              // 512 KB
  float* qp   = (float*)(ws + (512u << 10));               // 512 KB
  short* hhT  = (short*)(ws + (1u << 20));                 // 2 MB
  float* accP = (float*)(ws + (3u << 20));                 // 16 MB (3..19 MB)
  float* hh   = (float*)(ws + (3u << 20));                 // 4 MB, dead before accP written
  float* dP   = (float*)(ws + (19u << 20));                // 128 KB

  k_hh<<<NN / 16, 256, 0, stream>>>(h, eps, Wfc, hh);
  k_kq<<<(NN * 8) / 256, 256, 0, stream>>>(hh, Wk, Wq, kp, qp);
  k_tr<<<dim3(NN / 64, OF / 64), 256, 0, stream>>>(hh, hhT);
  k_attn<<<dim3(NN / QB, JSPLIT), 256, 0, stream>>>(As, kp, qp, hhT, accP, dP);
  k_comb<<<(NN * OF / 4) / 256, 256, 0, stream>>>(accP, dP, out);
}

// Round 8
// 497.711 us; speedup vs baseline: 1.1697x; 1.0052x over previous
//
#include <hip/hip_runtime.h>
#include <hip/hip_bf16.h>

#define NN     8192
#define INF_   256
#define OF     128
#define EMBD   16
#define JSPLIT 8
#define JCH    (NN / JSPLIT)   // 1024 j per wave
#define KV     32              // j per step
#define NSTEP  (JCH / KV)      // 32

typedef __attribute__((ext_vector_type(4)))  float          f32x4;
typedef __attribute__((ext_vector_type(16))) float          f32x16;
typedef __attribute__((ext_vector_type(8)))  short          s16x8;
typedef __attribute__((ext_vector_type(4)))  unsigned int   u32x4;
typedef __attribute__((ext_vector_type(4)))  unsigned short u16x4;

__device__ __forceinline__ unsigned short f2bf(float x) {
  unsigned u = __builtin_bit_cast(unsigned, x);
  return (unsigned short)((u + 0x7FFFu + ((u >> 16) & 1u)) >> 16);
}
__device__ __forceinline__ float bf2f(unsigned short h) {
  return __builtin_bit_cast(float, (unsigned)h << 16);
}
__device__ __forceinline__ float fexp2(float x) {
#if __has_builtin(__builtin_amdgcn_exp2f)
  return __builtin_amdgcn_exp2f(x);
#else
  return exp2f(x);
#endif
}

// ---- K1: hh = eps + h @ W_fc  (f32, register 2x4-tile, f32x4 loads) ----
__global__ __launch_bounds__(256) void k_hh(const float* __restrict__ h,
                                            const float* __restrict__ eps,
                                            const float* __restrict__ Wfc,
                                            float* __restrict__ hh) {
  const int tx = threadIdx.x & 31;
  const int ty = threadIdx.x >> 5;
  const int i0 = blockIdx.x * 16 + ty * 2;
  const int c  = tx * 4;
  f32x4 a0 = *(const f32x4*)&eps[(size_t)i0 * OF + c];
  f32x4 a1 = *(const f32x4*)&eps[(size_t)(i0 + 1) * OF + c];
  const float* h0 = h + (size_t)i0 * INF_;
  const float* h1 = h0 + INF_;
#pragma unroll 2
  for (int kk = 0; kk < INF_; kk += 4) {
    const f32x4 ha = *(const f32x4*)&h0[kk];
    const f32x4 hb = *(const f32x4*)&h1[kk];
#pragma unroll
    for (int u = 0; u < 4; ++u) {
      const f32x4 wv = *(const f32x4*)&Wfc[(size_t)(kk + u) * OF + c];
      a0 += ha[u] * wv;
      a1 += hb[u] * wv;
    }
  }
  *(f32x4*)&hh[(size_t)i0 * OF + c]       = a0;
  *(f32x4*)&hh[(size_t)(i0 + 1) * OF + c] = a1;
}

// ---- K2: hi/lo bf16 split of k' = (hh@W_k)*log2e and q = hh@W_q ----
__global__ __launch_bounds__(256) void k_kq(const float* __restrict__ hh,
                                            const float* __restrict__ Wk,
                                            const float* __restrict__ Wq,
                                            unsigned short* __restrict__ kph,
                                            unsigned short* __restrict__ kpl,
                                            unsigned short* __restrict__ qph,
                                            unsigned short* __restrict__ qpl) {
  const int t   = blockIdx.x * 256 + threadIdx.x;   // 8192*8 threads
  const int i   = t >> 3;
  const int sub = t & 7;
  const float* W = (sub < 4) ? Wk : Wq;
  const int e    = (sub & 3) * 4;
  const float* hr = hh + (size_t)i * OF;
  f32x4 acc = {0.f, 0.f, 0.f, 0.f};
#pragma unroll 4
  for (int o = 0; o < OF; o += 4) {
    const f32x4 hv = *(const f32x4*)&hr[o];
#pragma unroll
    for (int u = 0; u < 4; ++u) {
      const f32x4 wv = *(const f32x4*)&W[(size_t)(o + u) * EMBD + e];
      acc += hv[u] * wv;
    }
  }
  if (sub < 4) acc *= 1.4426950408889634f;   // fold log2(e) into k'
  u16x4 hi4, lo4;
#pragma unroll
  for (int u = 0; u < 4; ++u) {
    const unsigned short hb = f2bf(acc[u]);
    hi4[u] = hb;
    lo4[u] = f2bf(acc[u] - bf2f(hb));
  }
  unsigned short* dh = (sub < 4) ? kph : qph;
  unsigned short* dl = (sub < 4) ? kpl : qpl;
  *(u16x4*)&dh[(size_t)i * EMBD + e] = hi4;
  *(u16x4*)&dl[(size_t)i * EMBD + e] = lo4;
}

// ---- K3: hhT (bf16) [OF][NN] = transpose(hh) ----
__global__ __launch_bounds__(256) void k_tr(const float* __restrict__ hh,
                                            short* __restrict__ hhT) {
  __shared__ float tile[64][65];
  const int i0 = blockIdx.x * 64;
  const int o0 = blockIdx.y * 64;
  const int c = threadIdx.x & 63;
  const int r = threadIdx.x >> 6;
#pragma unroll
  for (int rr = 0; rr < 16; ++rr) {
    const int ii = rr * 4 + r;
    tile[ii][c] = hh[(size_t)(i0 + ii) * OF + o0 + c];
  }
  __syncthreads();
#pragma unroll
  for (int rr = 0; rr < 16; ++rr) {
    const int oo = rr * 4 + r;
    hhT[(size_t)(o0 + oo) * NN + i0 + c] = (short)f2bf(tile[c][oo]);
  }
}

// ---- K4: wave-autonomous fused attention partial (no LDS, no barriers) ----
// Each wave: 32 q-rows (qr..qr+31), j-chunk [j0, j0+1024).
// Scores S^T via 3x mfma 32x32x16 (hi/lo split); w = a_str * 2^(s-32);
// PV via mfma with w packed in-register (j-permuted A-rows make the score
// C-layout deliver j consecutively per register octet - no cross-lane ops).
__global__ __launch_bounds__(256, 2) void k_attn(
    const float* __restrict__ Astr,
    const unsigned short* __restrict__ kph,
    const unsigned short* __restrict__ kpl,
    const unsigned short* __restrict__ qph,
    const unsigned short* __restrict__ qpl,
    const short* __restrict__ hhT,
    float* __restrict__ accP,
    float* __restrict__ dP) {
  const int tid = threadIdx.x;
  const int l   = tid & 63;
  const int hi  = l >> 5;
  const int m   = l & 31;
  const int wid = blockIdx.x * 4 + (tid >> 6);
  const int p   = wid >> 8;            // j-split index 0..7
  const int qr  = (wid & 255) * 32;    // q-row base
  const int j0  = p * JCH;
  // swap bits 2<->3 of (l&31): score D-row r holds j = jperm(r); with this
  // permutation regs 0..7 hold j = 8*hi+{0..7}, regs 8..15 j = 16+8*hi+{0..7}
  const int jperm = (m & 19) | ((m & 8) >> 1) | ((m & 4) << 1);

  // persistent B-fragments of k' (cols = q-rows)
  const s16x8 kh = *(const s16x8*)(kph + (size_t)(qr + m) * EMBD + hi * 8);
  const s16x8 kl = *(const s16x8*)(kpl + (size_t)(qr + m) * EMBD + hi * 8);

  const float* ap          = Astr + (size_t)(qr + m) * NN + j0 + hi * 8;
  const unsigned short* qhb = qph + (size_t)(j0 + jperm) * EMBD + hi * 8;
  const unsigned short* qlb = qpl + (size_t)(j0 + jperm) * EMBD + hi * 8;
  const short* hp0 = hhT + (size_t)m * NN + j0 + hi * 8;
  const short* hp1 = hp0 + (size_t)32 * NN;
  const short* hp2 = hp0 + (size_t)64 * NN;
  const short* hp3 = hp0 + (size_t)96 * NN;

  f32x16 acc0 = {}, acc1 = {}, acc2 = {}, acc3 = {};
  float dpart = 0.f;

  // a_str register double-buffer, prefetch depth 2 steps
  f32x4 aA[4], aB[4];
  aA[0] = *(const f32x4*)(ap + 0);  aA[1] = *(const f32x4*)(ap + 4);
  aA[2] = *(const f32x4*)(ap + 16); aA[3] = *(const f32x4*)(ap + 20);
  aB[0] = *(const f32x4*)(ap + 32); aB[1] = *(const f32x4*)(ap + 36);
  aB[2] = *(const f32x4*)(ap + 48); aB[3] = *(const f32x4*)(ap + 52);

  auto STEP = [&](int rel, f32x4 (&ac)[4], int rel2) {
    // L2-resident loads first (issue order => fine-grained vmcnt waits)
    const size_t qo = (size_t)rel * EMBD;
    const s16x8 qh = *(const s16x8*)(qhb + qo);
    const s16x8 ql = *(const s16x8*)(qlb + qo);
    const s16x8 B00 = *(const s16x8*)(hp0 + rel);
    const s16x8 B01 = *(const s16x8*)(hp0 + rel + 16);
    const s16x8 B10 = *(const s16x8*)(hp1 + rel);
    const s16x8 B11 = *(const s16x8*)(hp1 + rel + 16);
    const s16x8 B20 = *(const s16x8*)(hp2 + rel);
    const s16x8 B21 = *(const s16x8*)(hp2 + rel + 16);
    const s16x8 B30 = *(const s16x8*)(hp3 + rel);
    const s16x8 B31 = *(const s16x8*)(hp3 + rel + 16);
    // scores (3-term hi/lo split; log2 units)
    f32x16 sc = {};
    sc = __builtin_amdgcn_mfma_f32_32x32x16_bf16(qh, kh, sc, 0, 0, 0);
    sc = __builtin_amdgcn_mfma_f32_32x32x16_bf16(qh, kl, sc, 0, 0, 0);
    sc = __builtin_amdgcn_mfma_f32_32x32x16_bf16(ql, kh, sc, 0, 0, 0);
    // weights
    float w[16];
    float d0 = 0.f, d1 = 0.f, d2 = 0.f, d3 = 0.f;
#pragma unroll
    for (int r = 0; r < 16; ++r) {
      const float wv = ac[r >> 2][r & 3] * fexp2(sc[r] - 32.0f);
      w[r] = wv;
      if ((r & 3) == 0) d0 += wv; else if ((r & 3) == 1) d1 += wv;
      else if ((r & 3) == 2) d2 += wv; else d3 += wv;
    }
    dpart += (d0 + d1) + (d2 + d3);
    // pack to PV A-fragments (j already consecutive per octet);
    // manual bf16x2 pack (u32) - avoids non-trivially-copyable HIP struct
    unsigned int pk[8];
#pragma unroll
    for (int d = 0; d < 8; ++d) {
      pk[d] = (unsigned int)f2bf(w[2 * d]) |
              ((unsigned int)f2bf(w[2 * d + 1]) << 16);
    }
    // prefetch a_str two steps ahead (HBM; no barrier => spans steps)
    const float* app = ap + rel2;
    ac[0] = *(const f32x4*)(app);      ac[1] = *(const f32x4*)(app + 4);
    ac[2] = *(const f32x4*)(app + 16); ac[3] = *(const f32x4*)(app + 20);
    const s16x8 A1 = __builtin_bit_cast(s16x8, (u32x4){pk[0], pk[1], pk[2], pk[3]});
    const s16x8 A2 = __builtin_bit_cast(s16x8, (u32x4){pk[4], pk[5], pk[6], pk[7]});
    acc0 = __builtin_amdgcn_mfma_f32_32x32x16_bf16(A1, B00, acc0, 0, 0, 0);
    acc0 = __builtin_amdgcn_mfma_f32_32x32x16_bf16(A2, B01, acc0, 0, 0, 0);
    acc1 = __builtin_amdgcn_mfma_f32_32x32x16_bf16(A1, B10, acc1, 0, 0, 0);
    acc1 = __builtin_amdgcn_mfma_f32_32x32x16_bf16(A2, B11, acc1, 0, 0, 0);
    acc2 = __builtin_amdgcn_mfma_f32_32x32x16_bf16(A1, B20, acc2, 0, 0, 0);
    acc2 = __builtin_amdgcn_mfma_f32_32x32x16_bf16(A2, B21, acc2, 0, 0, 0);
    acc3 = __builtin_amdgcn_mfma_f32_32x32x16_bf16(A1, B30, acc3, 0, 0, 0);
    acc3 = __builtin_amdgcn_mfma_f32_32x32x16_bf16(A2, B31, acc3, 0, 0, 0);
  };

  for (int tt = 0; tt < NSTEP; tt += 2) {
    STEP(tt * KV,       aA, ((tt + 2) & (NSTEP - 1)) * KV);
    STEP((tt + 1) * KV, aB, ((tt + 3) & (NSTEP - 1)) * KV);
  }

  // denominator: lane pair (l, l^32) holds complementary j-subsets of qrow m
  float dd = dpart + __shfl_xor(dpart, 32);
  if (hi == 0) dP[(size_t)p * NN + qr + m] = dd;

  // PV D-layout (verified): row = (reg&3)+8*(reg>>2)+4*hi, col = m
#pragma unroll
  for (int r = 0; r < 16; ++r) {
    const int row = (r & 3) + 8 * (r >> 2) + 4 * hi;
    float* o = accP + ((size_t)p * NN + qr + row) * OF + m;
    o[0]  = acc0[r];
    o[32] = acc1[r];
    o[64] = acc2[r];
    o[96] = acc3[r];
  }
}

// ---- K5: combine j-split partials (exact: plain sums) ----
__global__ __launch_bounds__(256) void k_comb(const float* __restrict__ accP,
                                              const float* __restrict__ dP,
                                              float* __restrict__ out) {
  const int idx = blockIdx.x * 256 + threadIdx.x;  // over NN*OF/4
  const int row = idx >> 5;
  const int cq  = (idx & 31) * 4;
  float D = 0.f;
  f32x4 s = {0.f, 0.f, 0.f, 0.f};
#pragma unroll
  for (int pp = 0; pp < JSPLIT; ++pp) {
    D += dP[(size_t)pp * NN + row];
    s += *(const f32x4*)&accP[((size_t)pp * NN + row) * OF + cq];
  }
  *(f32x4*)&out[(size_t)row * OF + cq] = s * (1.0f / D);
}

extern "C" void kernel_launch(void* const* d_in, const int* in_sizes, int n_in,
                              void* d_out, int out_size, void* d_ws, size_t ws_size,
                              hipStream_t stream) {
  const float* h   = (const float*)d_in[0];
  const float* eps = (const float*)d_in[1];
  const float* As  = (const float*)d_in[2];
  const float* Wfc = (const float*)d_in[3];
  const float* Wk  = (const float*)d_in[4];
  const float* Wq  = (const float*)d_in[5];
  float* out = (float*)d_out;

  char* ws = (char*)d_ws;
  unsigned short* kph = (unsigned short*)(ws);                 // 256 KB
  unsigned short* kpl = (unsigned short*)(ws + (256u << 10));  // 256 KB
  unsigned short* qph = (unsigned short*)(ws + (512u << 10));  // 256 KB
  unsigned short* qpl = (unsigned short*)(ws + (768u << 10));  // 256 KB
  short* hhT  = (short*)(ws + (1u << 20));                     // 2 MB
  float* hh   = (float*)(ws + (3u << 20));                     // 4 MB (dead before accP)
  float* accP = (float*)(ws + (3u << 20));                     // 32 MB, overlays hh
  float* dP   = (float*)(ws + (35u << 20));                    // 256 KB

  k_hh<<<NN / 16, 256, 0, stream>>>(h, eps, Wfc, hh);
  k_kq<<<(NN * 8) / 256, 256, 0, stream>>>(hh, Wk, Wq, kph, kpl, qph, qpl);
  k_tr<<<dim3(NN / 64, OF / 64), 256, 0, stream>>>(hh, hhT);
  k_attn<<<(NN / 32) * JSPLIT / 4, 256, 0, stream>>>(As, kph, kpl, qph, qpl, hhT, accP, dP);
  k_comb<<<(NN * OF / 4) / 256, 256, 0, stream>>>(accP, dP, out);
}

// Round 9
// 485.214 us; speedup vs baseline: 1.1998x; 1.0258x over previous
//
#include <hip/hip_runtime.h>
#include <hip/hip_bf16.h>

#define NN     8192
#define INF_   256
#define OF     128
#define EMBD   16
#define JSPLIT 16
#define JCH    (NN / JSPLIT)   // 512 j per wave
#define KV     32              // j per step
#define NSTEP  (JCH / KV)      // 16

typedef __attribute__((ext_vector_type(4)))  float          f32x4;
typedef __attribute__((ext_vector_type(16))) float          f32x16;
typedef __attribute__((ext_vector_type(8)))  short          s16x8;
typedef __attribute__((ext_vector_type(4)))  unsigned int   u32x4;
typedef __attribute__((ext_vector_type(4)))  unsigned short u16x4;

__device__ __forceinline__ unsigned short f2bf(float x) {
  unsigned u = __builtin_bit_cast(unsigned, x);
  return (unsigned short)((u + 0x7FFFu + ((u >> 16) & 1u)) >> 16);
}
__device__ __forceinline__ float bf2f(unsigned short h) {
  return __builtin_bit_cast(float, (unsigned)h << 16);
}
__device__ __forceinline__ float fexp2(float x) {
#if __has_builtin(__builtin_amdgcn_exp2f)
  return __builtin_amdgcn_exp2f(x);
#else
  return exp2f(x);
#endif
}

// ---- K0: zero the atomic accumulators (ws is poisoned 0xAA every launch) ----
__global__ __launch_bounds__(256) void k_zero(float* __restrict__ z) {
  const int i = blockIdx.x * 256 + threadIdx.x;
  *(f32x4*)&z[(size_t)i * 4] = (f32x4){0.f, 0.f, 0.f, 0.f};
}

// ---- K1: hh = eps + h @ W_fc  (f32, register 2x4-tile, f32x4 loads) ----
__global__ __launch_bounds__(256) void k_hh(const float* __restrict__ h,
                                            const float* __restrict__ eps,
                                            const float* __restrict__ Wfc,
                                            float* __restrict__ hh) {
  const int tx = threadIdx.x & 31;
  const int ty = threadIdx.x >> 5;
  const int i0 = blockIdx.x * 16 + ty * 2;
  const int c  = tx * 4;
  f32x4 a0 = *(const f32x4*)&eps[(size_t)i0 * OF + c];
  f32x4 a1 = *(const f32x4*)&eps[(size_t)(i0 + 1) * OF + c];
  const float* h0 = h + (size_t)i0 * INF_;
  const float* h1 = h0 + INF_;
#pragma unroll 2
  for (int kk = 0; kk < INF_; kk += 4) {
    const f32x4 ha = *(const f32x4*)&h0[kk];
    const f32x4 hb = *(const f32x4*)&h1[kk];
#pragma unroll
    for (int u = 0; u < 4; ++u) {
      const f32x4 wv = *(const f32x4*)&Wfc[(size_t)(kk + u) * OF + c];
      a0 += ha[u] * wv;
      a1 += hb[u] * wv;
    }
  }
  *(f32x4*)&hh[(size_t)i0 * OF + c]       = a0;
  *(f32x4*)&hh[(size_t)(i0 + 1) * OF + c] = a1;
}

// ---- K2: hi/lo bf16 split of k' = (hh@W_k)*log2e and q = hh@W_q ----
__global__ __launch_bounds__(256) void k_kq(const float* __restrict__ hh,
                                            const float* __restrict__ Wk,
                                            const float* __restrict__ Wq,
                                            unsigned short* __restrict__ kph,
                                            unsigned short* __restrict__ kpl,
                                            unsigned short* __restrict__ qph,
                                            unsigned short* __restrict__ qpl) {
  const int t   = blockIdx.x * 256 + threadIdx.x;   // 8192*8 threads
  const int i   = t >> 3;
  const int sub = t & 7;
  const float* W = (sub < 4) ? Wk : Wq;
  const int e    = (sub & 3) * 4;
  const float* hr = hh + (size_t)i * OF;
  f32x4 acc = {0.f, 0.f, 0.f, 0.f};
#pragma unroll 4
  for (int o = 0; o < OF; o += 4) {
    const f32x4 hv = *(const f32x4*)&hr[o];
#pragma unroll
    for (int u = 0; u < 4; ++u) {
      const f32x4 wv = *(const f32x4*)&W[(size_t)(o + u) * EMBD + e];
      acc += hv[u] * wv;
    }
  }
  if (sub < 4) acc *= 1.4426950408889634f;   // fold log2(e) into k'
  u16x4 hi4, lo4;
#pragma unroll
  for (int u = 0; u < 4; ++u) {
    const unsigned short hb = f2bf(acc[u]);
    hi4[u] = hb;
    lo4[u] = f2bf(acc[u] - bf2f(hb));
  }
  unsigned short* dh = (sub < 4) ? kph : qph;
  unsigned short* dl = (sub < 4) ? kpl : qpl;
  *(u16x4*)&dh[(size_t)i * EMBD + e] = hi4;
  *(u16x4*)&dl[(size_t)i * EMBD + e] = lo4;
}

// ---- K3: hhT (bf16) [OF][NN] = transpose(hh) ----
__global__ __launch_bounds__(256) void k_tr(const float* __restrict__ hh,
                                            short* __restrict__ hhT) {
  __shared__ float tile[64][65];
  const int i0 = blockIdx.x * 64;
  const int o0 = blockIdx.y * 64;
  const int c = threadIdx.x & 63;
  const int r = threadIdx.x >> 6;
#pragma unroll
  for (int rr = 0; rr < 16; ++rr) {
    const int ii = rr * 4 + r;
    tile[ii][c] = hh[(size_t)(i0 + ii) * OF + o0 + c];
  }
  __syncthreads();
#pragma unroll
  for (int rr = 0; rr < 16; ++rr) {
    const int oo = rr * 4 + r;
    hhT[(size_t)(o0 + oo) * NN + i0 + c] = (short)f2bf(tile[c][oo]);
  }
}

// ---- K4: wave-autonomous fused attention partial (no LDS, no barriers) ----
// Each wave: 32 q-rows (qr..qr+31), j-chunk [j0, j0+512).
// Scores S^T via 3x mfma 32x32x16 (hi/lo split); w = a_str * 2^(s-32);
// PV via mfma with w packed in-register; partials accumulated with
// device-scope f32 atomics into L3-resident accS/dS (exact up to fp order).
__global__ __launch_bounds__(256, 2) void k_attn(
    const float* __restrict__ Astr,
    const unsigned short* __restrict__ kph,
    const unsigned short* __restrict__ kpl,
    const unsigned short* __restrict__ qph,
    const unsigned short* __restrict__ qpl,
    const short* __restrict__ hhT,
    float* __restrict__ accS,
    float* __restrict__ dS) {
  const int tid = threadIdx.x;
  const int l   = tid & 63;
  const int hi  = l >> 5;
  const int m   = l & 31;
  const int wid = blockIdx.x * 4 + (tid >> 6);
  const int p   = wid >> 8;            // j-split index 0..15
  const int qr  = (wid & 255) * 32;    // q-row base
  const int j0  = p * JCH;
  // swap bits 2<->3 of (l&31): score D-row r holds j = jperm(r); with this
  // permutation regs 0..7 hold j = 8*hi+{0..7}, regs 8..15 j = 16+8*hi+{0..7}
  const int jperm = (m & 19) | ((m & 8) >> 1) | ((m & 4) << 1);

  // persistent B-fragments of k' (cols = q-rows)
  const s16x8 kh = *(const s16x8*)(kph + (size_t)(qr + m) * EMBD + hi * 8);
  const s16x8 kl = *(const s16x8*)(kpl + (size_t)(qr + m) * EMBD + hi * 8);

  const float* ap          = Astr + (size_t)(qr + m) * NN + j0 + hi * 8;
  const unsigned short* qhb = qph + (size_t)(j0 + jperm) * EMBD + hi * 8;
  const unsigned short* qlb = qpl + (size_t)(j0 + jperm) * EMBD + hi * 8;
  const short* hp0 = hhT + (size_t)m * NN + j0 + hi * 8;
  const short* hp1 = hp0 + (size_t)32 * NN;
  const short* hp2 = hp0 + (size_t)64 * NN;
  const short* hp3 = hp0 + (size_t)96 * NN;

  f32x16 acc0 = {}, acc1 = {}, acc2 = {}, acc3 = {};
  float dpart = 0.f;

  // a_str register double-buffer, prefetch depth 2 steps
  f32x4 aA[4], aB[4];
  aA[0] = *(const f32x4*)(ap + 0);  aA[1] = *(const f32x4*)(ap + 4);
  aA[2] = *(const f32x4*)(ap + 16); aA[3] = *(const f32x4*)(ap + 20);
  aB[0] = *(const f32x4*)(ap + 32); aB[1] = *(const f32x4*)(ap + 36);
  aB[2] = *(const f32x4*)(ap + 48); aB[3] = *(const f32x4*)(ap + 52);

  auto STEP = [&](int rel, f32x4 (&ac)[4], int rel2) {
    // L2-resident loads first (issue order => fine-grained vmcnt waits)
    const size_t qo = (size_t)rel * EMBD;
    const s16x8 qh = *(const s16x8*)(qhb + qo);
    const s16x8 ql = *(const s16x8*)(qlb + qo);
    const s16x8 B00 = *(const s16x8*)(hp0 + rel);
    const s16x8 B01 = *(const s16x8*)(hp0 + rel + 16);
    const s16x8 B10 = *(const s16x8*)(hp1 + rel);
    const s16x8 B11 = *(const s16x8*)(hp1 + rel + 16);
    const s16x8 B20 = *(const s16x8*)(hp2 + rel);
    const s16x8 B21 = *(const s16x8*)(hp2 + rel + 16);
    const s16x8 B30 = *(const s16x8*)(hp3 + rel);
    const s16x8 B31 = *(const s16x8*)(hp3 + rel + 16);
    // scores (3-term hi/lo split; log2 units)
    f32x16 sc = {};
    sc = __builtin_amdgcn_mfma_f32_32x32x16_bf16(qh, kh, sc, 0, 0, 0);
    sc = __builtin_amdgcn_mfma_f32_32x32x16_bf16(qh, kl, sc, 0, 0, 0);
    sc = __builtin_amdgcn_mfma_f32_32x32x16_bf16(ql, kh, sc, 0, 0, 0);
    // weights
    float w[16];
    float d0 = 0.f, d1 = 0.f, d2 = 0.f, d3 = 0.f;
#pragma unroll
    for (int r = 0; r < 16; ++r) {
      const float wv = ac[r >> 2][r & 3] * fexp2(sc[r] - 32.0f);
      w[r] = wv;
      if ((r & 3) == 0) d0 += wv; else if ((r & 3) == 1) d1 += wv;
      else if ((r & 3) == 2) d2 += wv; else d3 += wv;
    }
    dpart += (d0 + d1) + (d2 + d3);
    // pack to PV A-fragments (j already consecutive per octet);
    // manual bf16x2 pack (u32) - avoids non-trivially-copyable HIP struct
    unsigned int pk[8];
#pragma unroll
    for (int d = 0; d < 8; ++d) {
      pk[d] = (unsigned int)f2bf(w[2 * d]) |
              ((unsigned int)f2bf(w[2 * d + 1]) << 16);
    }
    // prefetch a_str two steps ahead (HBM; no barrier => spans steps)
    const float* app = ap + rel2;
    ac[0] = *(const f32x4*)(app);      ac[1] = *(const f32x4*)(app + 4);
    ac[2] = *(const f32x4*)(app + 16); ac[3] = *(const f32x4*)(app + 20);
    const s16x8 A1 = __builtin_bit_cast(s16x8, (u32x4){pk[0], pk[1], pk[2], pk[3]});
    const s16x8 A2 = __builtin_bit_cast(s16x8, (u32x4){pk[4], pk[5], pk[6], pk[7]});
    acc0 = __builtin_amdgcn_mfma_f32_32x32x16_bf16(A1, B00, acc0, 0, 0, 0);
    acc0 = __builtin_amdgcn_mfma_f32_32x32x16_bf16(A2, B01, acc0, 0, 0, 0);
    acc1 = __builtin_amdgcn_mfma_f32_32x32x16_bf16(A1, B10, acc1, 0, 0, 0);
    acc1 = __builtin_amdgcn_mfma_f32_32x32x16_bf16(A2, B11, acc1, 0, 0, 0);
    acc2 = __builtin_amdgcn_mfma_f32_32x32x16_bf16(A1, B20, acc2, 0, 0, 0);
    acc2 = __builtin_amdgcn_mfma_f32_32x32x16_bf16(A2, B21, acc2, 0, 0, 0);
    acc3 = __builtin_amdgcn_mfma_f32_32x32x16_bf16(A1, B30, acc3, 0, 0, 0);
    acc3 = __builtin_amdgcn_mfma_f32_32x32x16_bf16(A2, B31, acc3, 0, 0, 0);
  };

  for (int tt = 0; tt < NSTEP; tt += 2) {
    STEP(tt * KV,       aA, ((tt + 2) & (NSTEP - 1)) * KV);
    STEP((tt + 1) * KV, aB, ((tt + 3) & (NSTEP - 1)) * KV);
  }

  // denominator: lane pair (l, l^32) holds complementary j-subsets of qrow m
  float dd = dpart + __shfl_xor(dpart, 32);
  if (hi == 0) atomicAdd(&dS[qr + m], dd);

  // PV D-layout (verified): row = (reg&3)+8*(reg>>2)+4*hi, col = m
#pragma unroll
  for (int r = 0; r < 16; ++r) {
    const int row = (r & 3) + 8 * (r >> 2) + 4 * hi;
    float* o = accS + (size_t)(qr + row) * OF + m;
    atomicAdd(o + 0,  acc0[r]);
    atomicAdd(o + 32, acc1[r]);
    atomicAdd(o + 64, acc2[r]);
    atomicAdd(o + 96, acc3[r]);
  }
}

// ---- K5: final divide ----
__global__ __launch_bounds__(256) void k_div(const float* __restrict__ accS,
                                             const float* __restrict__ dS,
                                             float* __restrict__ out) {
  const int idx = blockIdx.x * 256 + threadIdx.x;  // over NN*OF/4
  const int row = idx >> 5;
  const int cq  = (idx & 31) * 4;
  const f32x4 s = *(const f32x4*)&accS[(size_t)row * OF + cq];
  *(f32x4*)&out[(size_t)row * OF + cq] = s * (1.0f / dS[row]);
}

extern "C" void kernel_launch(void* const* d_in, const int* in_sizes, int n_in,
                              void* d_out, int out_size, void* d_ws, size_t ws_size,
                              hipStream_t stream) {
  const float* h   = (const float*)d_in[0];
  const float* eps = (const float*)d_in[1];
  const float* As  = (const float*)d_in[2];
  const float* Wfc = (const float*)d_in[3];
  const float* Wk  = (const float*)d_in[4];
  const float* Wq  = (const float*)d_in[5];
  float* out = (float*)d_out;

  char* ws = (char*)d_ws;
  unsigned short* kph = (unsigned short*)(ws);                 // 256 KB
  unsigned short* kpl = (unsigned short*)(ws + (256u << 10));  // 256 KB
  unsigned short* qph = (unsigned short*)(ws + (512u << 10));  // 256 KB
  unsigned short* qpl = (unsigned short*)(ws + (768u << 10));  // 256 KB
  short* hhT  = (short*)(ws + (1u << 20));                     // 2 MB
  float* hh   = (float*)(ws + (3u << 20));                     // 4 MB
  float* accS = (float*)(ws + (7u << 20));                     // 4 MB
  float* dS   = (float*)(ws + (11u << 20));                    // 32 KB (contiguous after accS)

  // zero accS (4MB) + dS (32KB): (NN*OF + NN)/4 f32x4 stores
  k_zero<<<(NN * OF + NN) / (256 * 4), 256, 0, stream>>>(accS);
  k_hh<<<NN / 16, 256, 0, stream>>>(h, eps, Wfc, hh);
  k_kq<<<(NN * 8) / 256, 256, 0, stream>>>(hh, Wk, Wq, kph, kpl, qph, qpl);
  k_tr<<<dim3(NN / 64, OF / 64), 256, 0, stream>>>(hh, hhT);
  k_attn<<<(NN / 32) * JSPLIT / 4, 256, 0, stream>>>(As, kph, kpl, qph, qpl, hhT, accS, dS);
  k_div<<<(NN * OF / 4) / 256, 256, 0, stream>>>(accS, dS, out);
}